// Round 7
// baseline (208.300 us; speedup 1.0000x reference)
//
#include <hip/hip_runtime.h>
#include <math.h>

#define BS 32
#define NQ 900
#define NC 1203
#define NT 100
#define SLOTS 15   // ceil(900/64)

// ---------------------------------------------------------------------------
// Kernel 1: cost matrix (math identical to passing rounds) + optional CT.
// ---------------------------------------------------------------------------
__global__ __launch_bounds__(128) void cost_kernel(
    const float* __restrict__ logits, const float* __restrict__ boxes,
    const int* __restrict__ tlabels, const float* __restrict__ tboxes,
    float* __restrict__ C, float* __restrict__ CT)
{
    int bq = blockIdx.x;
    int b = bq / NQ, q = bq % NQ;
    int t = threadIdx.x;

    const float* pb = boxes + (size_t)(b * NQ + q) * 4;
    float pcx = pb[0], pcy = pb[1], pw = pb[2], ph = pb[3];

    if (t < NT) {
        int id = tlabels[b * NT + t];
        float x = logits[(size_t)(b * NQ + q) * NC + id];
        float prob = 1.0f / (1.0f + expf(-x));
        float neg = 0.75f * (prob * prob) * (-logf(1.0f - prob + 1e-8f));
        float pos = 0.25f * ((1.0f - prob) * (1.0f - prob)) * (-logf(prob + 1e-8f));
        float cclass = pos - neg;

        const float* tb = tboxes + (size_t)(b * NT + t) * 4;
        float tcx = tb[0], tcy = tb[1], tw = tb[2], th = tb[3];
        float cbbox = fabsf(pcx - tcx) + fabsf(pcy - tcy) + fabsf(pw - tw) + fabsf(ph - th);

        float p0 = pcx - 0.5f * pw, p1 = pcy - 0.5f * ph;
        float p2 = pcx + 0.5f * pw, p3 = pcy + 0.5f * ph;
        float t0 = tcx - 0.5f * tw, t1 = tcy - 0.5f * th;
        float t2 = tcx + 0.5f * tw, t3 = tcy + 0.5f * th;
        float area1 = (p2 - p0) * (p3 - p1);
        float area2 = (t2 - t0) * (t3 - t1);
        float ltx = fmaxf(p0, t0), lty = fmaxf(p1, t1);
        float rbx = fminf(p2, t2), rby = fminf(p3, t3);
        float wx = fmaxf(rbx - ltx, 0.0f), wy = fmaxf(rby - lty, 0.0f);
        float inter = wx * wy;
        float uni = area1 + area2 - inter;
        float iou = inter / uni;
        float l2x = fminf(p0, t0), l2y = fminf(p1, t1);
        float r2x = fmaxf(p2, t2), r2y = fmaxf(p3, t3);
        float hx = fmaxf(r2x - l2x, 0.0f), hy = fmaxf(r2y - l2y, 0.0f);
        float hull = hx * hy;
        float giou = iou - (hull - uni) / hull;

        float val = 5.0f * cbbox + 2.0f * cclass + 2.0f * (-giou);
        C[(size_t)(b * NQ + q) * NT + t] = val;
        if (CT) CT[((size_t)b * NT + t) * NQ + q] = val;
    }
}

// ---------------------------------------------------------------------------
// Kernel 2: per-row min+argmin of cost.T reading C directly (ws-independent).
// One 256-thread block per (b,t). Stash in pred/tgt region (jv overwrites).
// ---------------------------------------------------------------------------
__global__ __launch_bounds__(256) void rowmin2_kernel(
    const float* __restrict__ C, float* __restrict__ u0, int* __restrict__ amin)
{
    int bi = blockIdx.x;                    // b*NT + t
    int b = bi / NT, t = bi % NT;
    const float* Cbt = C + (size_t)b * NQ * NT + t;   // element q at Cbt[q*NT]
    int tid = threadIdx.x;
    int w = tid >> 6, lane = tid & 63;

    float best = __builtin_huge_valf();
    int bq = NQ;
    for (int q = tid; q < NQ; q += 256) {   // ascending per thread -> strict < keeps smallest q
        float c = Cbt[(size_t)q * NT];
        if (c < best) { best = c; bq = q; }
    }
    for (int off = 32; off; off >>= 1) {
        float ov = __shfl_down(best, off);
        int  oq = __shfl_down(bq, off);
        if (ov < best || (ov == best && oq < bq)) { best = ov; bq = oq; }
    }
    __shared__ float sv[4];
    __shared__ int sj[4];
    if (lane == 0) { sv[w] = best; sj[w] = bq; }
    __syncthreads();
    if (tid == 0) {
        float bv = sv[0]; int bj = sj[0];
        for (int k = 1; k < 4; ++k) {
            if (sv[k] < bv || (sv[k] == bv && sj[k] < bj)) { bv = sv[k]; bj = sj[k]; }
        }
        u0[bi] = bv; amin[bi] = bj;
    }
}

// ---------------------------------------------------------------------------
// Kernel 3: JV solver, one wave per batch. NO ARR: greedy claim, then
// deferred-dual Dijkstra (scipy rectangular_lsap) directly for each free row.
// Post-greedy duals are feasible+tight and ~800/900 columns are free, so each
// Dijkstra terminates in ~2-3 pops. Exact optimum == reference (unique).
// ---------------------------------------------------------------------------
template<bool USE_CT>
__global__ __launch_bounds__(64) void jv_kernel(
    const float* __restrict__ C, const float* __restrict__ CT,
    const float* __restrict__ u0g, const int* __restrict__ aming,
    float* __restrict__ pred_out, float* __restrict__ tgt_out)
{
    int b = blockIdx.x;
    const float* Cb  = C + (size_t)b * NQ * NT;
    const float* CTb = USE_CT ? CT + (size_t)b * NT * NQ : nullptr;
    int lane = threadIdx.x;
    const double INF = __builtin_huge_val();

    __shared__ double u[NT];
    __shared__ double vsh[NQ];
    __shared__ double spsh[NQ];
    __shared__ int path[NQ];
    __shared__ int row4col[NQ];
    __shared__ int col4row[NT];
    __shared__ int aminsh[NT];
    __shared__ int freeRows[NT + 4];
    __shared__ int srList[136];
    __shared__ int nFreeSh;

    // ---- phase A: init from stash ----
    for (int j = lane; j < NQ; j += 64) { vsh[j] = 0.0; row4col[j] = 0x7fffffff; }
    for (int i = lane; i < NT; i += 64) {
        u[i] = (double)u0g[b * NT + i];
        aminsh[i] = aming[b * NT + i];
    }
    if (lane == 0) nFreeSh = 0;
    __syncthreads();

    // ---- phase B: greedy claim (smallest row wins a contested column) ----
    for (int i = lane; i < NT; i += 64) atomicMin(&row4col[aminsh[i]], i);
    __syncthreads();
    if (lane == 0) {
        int n = 0;
        for (int i = 0; i < NT; ++i) {
            int j = aminsh[i];
            if (row4col[j] == i) col4row[i] = j;
            else { col4row[i] = -1; freeRows[n++] = i; }   // ascending i
        }
        nFreeSh = n;
    }
    __syncthreads();
    for (int j = lane; j < NQ; j += 64)
        if (row4col[j] == 0x7fffffff) row4col[j] = -1;
    __syncthreads();

    // ---- phase D: deferred-dual Dijkstra per free row ----
    int nf = nFreeSh;
    for (int f = 0; f < nf; ++f) {
        int curRow = freeRows[f];
        double minv[SLOTS];
        #pragma unroll
        for (int k = 0; k < SLOTS; ++k) minv[k] = INF;
        unsigned scMask = 0;
        double minVal = 0.0;
        int i = curRow, nIter = 0, sink = -1;

        while (sink < 0) {
            if (lane == 0) srList[nIter] = i;
            double ui = u[i];
            const float* rowp = USE_CT ? (CTb + (size_t)i * NQ) : nullptr;
            double lbest = INF; int lbestj = 0x7fffffff;
            #pragma unroll
            for (int k = 0; k < SLOTS; ++k) {
                int j = (k << 6) + lane;
                bool ok = (k < SLOTS - 1) || (j < NQ);
                if (ok && !((scMask >> k) & 1u)) {
                    float c = USE_CT ? rowp[j] : Cb[(size_t)j * NT + i];
                    double cur = minVal + (double)c - ui - vsh[j];
                    if (cur < minv[k]) { minv[k] = cur; spsh[j] = cur; path[j] = i; }
                    double mk = minv[k];
                    if (mk < lbest || (mk == lbest && j < lbestj)) { lbest = mk; lbestj = j; }
                }
            }
            for (int off = 32; off; off >>= 1) {
                double ov = __shfl_down(lbest, off);
                int  oj = __shfl_down(lbestj, off);
                if (ov < lbest || (ov == lbest && oj < lbestj)) { lbest = ov; lbestj = oj; }
            }
            minVal = __shfl(lbest, 0);
            int j1 = __shfl(lbestj, 0);
            if (lane == (j1 & 63)) scMask |= (1u << (j1 >> 6));
            int r = row4col[j1];
            nIter++;
            if (r < 0 || nIter >= 127) sink = j1;
            else i = r;
        }
        __syncthreads();   // spsh/path stable before dual updates

        if (lane == 0) {
            u[curRow] += minVal;
            for (int t2 = 1; t2 < nIter; ++t2) {
                int ri = srList[t2];
                u[ri] += minVal - spsh[col4row[ri]];   // pre-augment col4row
            }
        }
        #pragma unroll
        for (int k = 0; k < SLOTS; ++k) {
            int j = (k << 6) + lane;
            bool ok = (k < SLOTS - 1) || (j < NQ);
            if (ok && ((scMask >> k) & 1u)) vsh[j] -= minVal - minv[k];
        }
        if (lane == 0) {   // augment
            int j = sink, g2 = 0;
            while (g2++ < 128) {
                int ri = path[j];
                row4col[j] = ri;
                int t2 = col4row[ri]; col4row[ri] = j;
                j = t2;
                if (ri == curRow) break;
            }
        }
        __syncthreads();
    }

    // ---- epilogue: rank-sort col4row, write indices ----
    for (int i2 = lane; i2 < NT; i2 += 64) {
        int ci = col4row[i2];
        int rank = 0;
        for (int k2 = 0; k2 < NT; ++k2) rank += (col4row[k2] < ci);
        pred_out[b * NT + rank] = (float)ci;
        tgt_out[b * NT + rank] = (float)i2;
    }
}

extern "C" void kernel_launch(void* const* d_in, const int* in_sizes, int n_in,
                              void* d_out, int out_size, void* d_ws, size_t ws_size,
                              hipStream_t stream) {
    const float* logits = (const float*)d_in[0];
    const float* boxes  = (const float*)d_in[1];
    const int*   tlab   = (const int*)d_in[2];
    const float* tboxes = (const float*)d_in[3];

    float* out  = (float*)d_out;
    float* C    = out;                                  // 32*900*100
    float* pred = out + (size_t)BS * NQ * NT;           // 32*100
    float* tgt  = pred + BS * NT;                       // 32*100

    const size_t ctBytes = (size_t)BS * NT * NQ * sizeof(float);
    float* CT = (ws_size >= ctBytes) ? (float*)d_ws : nullptr;

    cost_kernel<<<BS * NQ, 128, 0, stream>>>(logits, boxes, tlab, tboxes, C, CT);

    // ws-independent parallel row-min; stash in pred/tgt region (jv overwrites)
    float* u0 = pred;          // 3200 floats
    int* amin = (int*)tgt;     // 3200 ints
    rowmin2_kernel<<<BS * NT, 256, 0, stream>>>(C, u0, amin);

    if (CT) jv_kernel<true ><<<BS, 64, 0, stream>>>(C, CT, u0, amin, pred, tgt);
    else    jv_kernel<false><<<BS, 64, 0, stream>>>(C, nullptr, u0, amin, pred, tgt);
}

// Round 9
// 149.642 us; speedup vs baseline: 1.3920x; 1.3920x over previous
//
#include <hip/hip_runtime.h>
#include <math.h>

#define BS 32
#define NQ 900
#define NC 1203
#define NT 100
#define SLOTS 15   // ceil(900/64)

// Static device-side scratch: no hipMalloc, graph-capture safe, fully
// rewritten every call before any read (deterministic).
__device__ float g_CT[(size_t)BS * NT * NQ];   // 11.5 MB: CT[b][t][q]
__device__ float g_u0[BS * NT];
__device__ int   g_amin[BS * NT];

// ---------------------------------------------------------------------------
// Kernel 1: cost matrix (math identical to all passing rounds).
// ---------------------------------------------------------------------------
__global__ __launch_bounds__(128) void cost_kernel(
    const float* __restrict__ logits, const float* __restrict__ boxes,
    const int* __restrict__ tlabels, const float* __restrict__ tboxes,
    float* __restrict__ C)
{
    int bq = blockIdx.x;
    int b = bq / NQ, q = bq % NQ;
    int t = threadIdx.x;

    const float* pb = boxes + (size_t)(b * NQ + q) * 4;
    float pcx = pb[0], pcy = pb[1], pw = pb[2], ph = pb[3];

    if (t < NT) {
        int id = tlabels[b * NT + t];
        float x = logits[(size_t)(b * NQ + q) * NC + id];
        float prob = 1.0f / (1.0f + expf(-x));
        float neg = 0.75f * (prob * prob) * (-logf(1.0f - prob + 1e-8f));
        float pos = 0.25f * ((1.0f - prob) * (1.0f - prob)) * (-logf(prob + 1e-8f));
        float cclass = pos - neg;

        const float* tb = tboxes + (size_t)(b * NT + t) * 4;
        float tcx = tb[0], tcy = tb[1], tw = tb[2], th = tb[3];
        float cbbox = fabsf(pcx - tcx) + fabsf(pcy - tcy) + fabsf(pw - tw) + fabsf(ph - th);

        float p0 = pcx - 0.5f * pw, p1 = pcy - 0.5f * ph;
        float p2 = pcx + 0.5f * pw, p3 = pcy + 0.5f * ph;
        float t0 = tcx - 0.5f * tw, t1 = tcy - 0.5f * th;
        float t2 = tcx + 0.5f * tw, t3 = tcy + 0.5f * th;
        float area1 = (p2 - p0) * (p3 - p1);
        float area2 = (t2 - t0) * (t3 - t1);
        float ltx = fmaxf(p0, t0), lty = fmaxf(p1, t1);
        float rbx = fminf(p2, t2), rby = fminf(p3, t3);
        float wx = fmaxf(rbx - ltx, 0.0f), wy = fmaxf(rby - lty, 0.0f);
        float inter = wx * wy;
        float uni = area1 + area2 - inter;
        float iou = inter / uni;
        float l2x = fminf(p0, t0), l2y = fminf(p1, t1);
        float r2x = fmaxf(p2, t2), r2y = fmaxf(p3, t3);
        float hx = fmaxf(r2x - l2x, 0.0f), hy = fmaxf(r2y - l2y, 0.0f);
        float hull = hx * hy;
        float giou = iou - (hull - uni) / hull;

        C[(size_t)(b * NQ + q) * NT + t] =
            5.0f * cbbox + 2.0f * cclass + 2.0f * (-giou);
    }
}

// ---------------------------------------------------------------------------
// Kernel 2: LDS-tiled transpose C[b][q][t] -> g_CT[b][t][q], both sides
// coalesced. Tile [64][101] (pad -> odd stride -> bank-conflict-free).
// ---------------------------------------------------------------------------
__global__ __launch_bounds__(256) void transpose_kernel(const float* __restrict__ C)
{
    __shared__ float tile[64][101];
    int b = blockIdx.x / 15;           // 15 q-chunks of 64 (14*64+4=900)
    int chunk = blockIdx.x % 15;
    int q0 = chunk * 64;
    int nq = (q0 + 64 <= NQ) ? 64 : (NQ - q0);
    int tid = threadIdx.x;

    const float* Cb = C + (size_t)b * NQ * NT;
    for (int e = tid; e < nq * NT; e += 256) {
        int qq = e / NT, t = e % NT;
        tile[qq][t] = Cb[(size_t)(q0 + qq) * NT + t];
    }
    __syncthreads();
    float* CTb = g_CT + (size_t)b * NT * NQ;
    for (int e = tid; e < NT * nq; e += 256) {
        int t = e / nq, qq = e % nq;
        CTb[(size_t)t * NQ + q0 + qq] = tile[qq][t];
    }
}

// ---------------------------------------------------------------------------
// Kernel 3: per-row min+argmin of cost.T from g_CT (coalesced), one wave/row.
// ---------------------------------------------------------------------------
__global__ __launch_bounds__(64) void rowmin_kernel()
{
    int bi = blockIdx.x;                    // b*NT + t
    const float* row = g_CT + (size_t)bi * NQ;
    int tid = threadIdx.x;
    float bestv = __builtin_huge_valf();
    int bestj = NQ;
    #pragma unroll
    for (int k = 0; k < SLOTS; ++k) {
        int j = (k << 6) + tid;
        if ((k < SLOTS - 1) || (j < NQ)) {
            float c = row[j];
            if (c < bestv) { bestv = c; bestj = j; }
        }
    }
    for (int off = 32; off; off >>= 1) {
        float ov = __shfl_down(bestv, off);
        int  oj = __shfl_down(bestj, off);
        if (ov < bestv || (ov == bestv && oj < bestj)) { bestv = ov; bestj = oj; }
    }
    if (tid == 0) { g_u0[bi] = bestv; g_amin[bi] = bestj; }
}

// ---------------------------------------------------------------------------
// Kernel 4: JV solver, one wave per batch, all scans coalesced from g_CT.
// B: greedy claim  C: ARR with 2-visit cap  D: deferred-dual Dijkstra.
// Exact LSA optimum == reference (optimum unique for continuous random costs).
// ---------------------------------------------------------------------------
__global__ __launch_bounds__(64) void jv_kernel(
    float* __restrict__ pred_out, float* __restrict__ tgt_out)
{
    int b = blockIdx.x;
    const float* CTb = g_CT + (size_t)b * NT * NQ;
    int lane = threadIdx.x;
    const double INF = __builtin_huge_val();

    __shared__ double u[NT];
    __shared__ double vsh[NQ];
    __shared__ double spsh[NQ];
    __shared__ int path[NQ];
    __shared__ int row4col[NQ];
    __shared__ int col4row[NT];
    __shared__ int aminsh[NT];
    __shared__ int freeRows[NT + 4];
    __shared__ int parked[NT];
    __shared__ int srList[136];
    __shared__ unsigned char visits[NT];
    __shared__ int nFreeSh, nParkSh;

    // ---- phase A: init from stash ----
    for (int j = lane; j < NQ; j += 64) { vsh[j] = 0.0; row4col[j] = 0x7fffffff; }
    for (int i = lane; i < NT; i += 64) {
        visits[i] = 0;
        u[i] = (double)g_u0[b * NT + i];
        aminsh[i] = g_amin[b * NT + i];
    }
    if (lane == 0) { nFreeSh = 0; nParkSh = 0; }
    __syncthreads();

    // ---- phase B: greedy claim (smallest row wins a contested column) ----
    for (int i = lane; i < NT; i += 64) atomicMin(&row4col[aminsh[i]], i);
    __syncthreads();
    if (lane == 0) {
        int n = 0;
        for (int i = 0; i < NT; ++i) {
            int j = aminsh[i];
            if (row4col[j] == i) col4row[i] = j;
            else { col4row[i] = -1; freeRows[n++] = i; }
        }
        nFreeSh = n;
    }
    __syncthreads();
    for (int j = lane; j < NQ; j += 64)
        if (row4col[j] == 0x7fffffff) row4col[j] = -1;
    __syncthreads();

    // ---- phase C: ARR with 2-visit cap ----
    int guard = 0;
    while (guard++ < 300) {
        int nf = nFreeSh;                          // uniform
        if (nf == 0) break;
        int i = freeRows[nf - 1];                  // uniform
        if (visits[i] >= 2) {                      // park for Dijkstra
            if (lane == 0) { nFreeSh = nf - 1; parked[nParkSh] = i; nParkSh++; }
            __syncthreads();
            continue;
        }
        if (lane == 0) visits[i]++;

        const float* rowp = CTb + (size_t)i * NQ;
        double m1 = INF, m2 = INF; int j1 = 0;
        #pragma unroll
        for (int k = 0; k < SLOTS; ++k) {
            int j = (k << 6) + lane;
            if ((k < SLOTS - 1) || (j < NQ)) {
                float c = rowp[j];
                double cur = (double)c - vsh[j];
                if (cur < m1) { m2 = m1; m1 = cur; j1 = j; }
                else if (cur < m2) m2 = cur;
            }
        }
        for (int off = 32; off; off >>= 1) {
            double o1 = __shfl_down(m1, off); int oj = __shfl_down(j1, off);
            double o2 = __shfl_down(m2, off);
            if (o1 < m1 || (o1 == m1 && oj < j1)) { m2 = fmin(m1, o2); m1 = o1; j1 = oj; }
            else m2 = fmin(m2, o1);
        }
        if (lane == 0) {
            u[i] = m2;
            vsh[j1] -= (m2 - m1);
            int inc = row4col[j1];
            row4col[j1] = i; col4row[i] = j1;
            int n = nf - 1;
            if (inc >= 0) { col4row[inc] = -1; freeRows[n++] = inc; }
            nFreeSh = n;
        }
        __syncthreads();
    }
    // spill anything left to parked
    if (lane == 0) {
        while (nFreeSh > 0) { nFreeSh--; parked[nParkSh] = freeRows[nFreeSh]; nParkSh++; }
    }
    __syncthreads();

    // ---- phase D: deferred-dual Dijkstra (scipy-style) for parked rows ----
    int np = nParkSh;
    for (int f = 0; f < np; ++f) {
        int curRow = parked[f];
        double minv[SLOTS];
        #pragma unroll
        for (int k = 0; k < SLOTS; ++k) minv[k] = INF;
        unsigned scMask = 0;
        double minVal = 0.0;
        int i = curRow, nIter = 0, sink = -1;

        while (sink < 0) {
            if (lane == 0) srList[nIter] = i;
            double ui = u[i];
            const float* rowp = CTb + (size_t)i * NQ;
            double lbest = INF; int lbestj = 0x7fffffff;
            #pragma unroll
            for (int k = 0; k < SLOTS; ++k) {
                int j = (k << 6) + lane;
                bool inb = (k < SLOTS - 1) || (j < NQ);
                float c = inb ? rowp[j] : 0.0f;
                if (inb && !((scMask >> k) & 1u)) {
                    double cur = minVal + (double)c - ui - vsh[j];
                    if (cur < minv[k]) { minv[k] = cur; spsh[j] = cur; path[j] = i; }
                    double mk = minv[k];
                    if (mk < lbest || (mk == lbest && j < lbestj)) { lbest = mk; lbestj = j; }
                }
            }
            for (int off = 32; off; off >>= 1) {
                double ov = __shfl_down(lbest, off);
                int  oj = __shfl_down(lbestj, off);
                if (ov < lbest || (ov == lbest && oj < lbestj)) { lbest = ov; lbestj = oj; }
            }
            minVal = __shfl(lbest, 0);
            int j1 = __shfl(lbestj, 0);
            if (lane == (j1 & 63)) scMask |= (1u << (j1 >> 6));
            int r = row4col[j1];
            nIter++;
            if (r < 0 || nIter >= 127) sink = j1;
            else i = r;
        }
        __syncthreads();   // spsh/path stable before dual updates

        if (lane == 0) {
            u[curRow] += minVal;
            for (int t2 = 1; t2 < nIter; ++t2) {
                int ri = srList[t2];
                u[ri] += minVal - spsh[col4row[ri]];   // pre-augment col4row
            }
        }
        #pragma unroll
        for (int k = 0; k < SLOTS; ++k) {
            int j = (k << 6) + lane;
            bool ok = (k < SLOTS - 1) || (j < NQ);
            if (ok && ((scMask >> k) & 1u)) vsh[j] -= minVal - minv[k];
        }
        if (lane == 0) {   // augment
            int j = sink, g2 = 0;
            while (g2++ < 128) {
                int ri = path[j];
                row4col[j] = ri;
                int t2 = col4row[ri]; col4row[ri] = j;
                j = t2;
                if (ri == curRow) break;
            }
        }
        __syncthreads();
    }

    // ---- epilogue: rank-sort col4row, write indices ----
    for (int i2 = lane; i2 < NT; i2 += 64) {
        int ci = col4row[i2];
        int rank = 0;
        for (int k2 = 0; k2 < NT; ++k2) rank += (col4row[k2] < ci);
        pred_out[b * NT + rank] = (float)ci;
        tgt_out[b * NT + rank] = (float)i2;
    }
}

extern "C" void kernel_launch(void* const* d_in, const int* in_sizes, int n_in,
                              void* d_out, int out_size, void* d_ws, size_t ws_size,
                              hipStream_t stream) {
    const float* logits = (const float*)d_in[0];
    const float* boxes  = (const float*)d_in[1];
    const int*   tlab   = (const int*)d_in[2];
    const float* tboxes = (const float*)d_in[3];

    float* out  = (float*)d_out;
    float* C    = out;                                  // 32*900*100
    float* pred = out + (size_t)BS * NQ * NT;           // 32*100
    float* tgt  = pred + BS * NT;                       // 32*100

    cost_kernel<<<BS * NQ, 128, 0, stream>>>(logits, boxes, tlab, tboxes, C);
    transpose_kernel<<<BS * 15, 256, 0, stream>>>(C);
    rowmin_kernel<<<BS * NT, 64, 0, stream>>>();
    jv_kernel<<<BS, 64, 0, stream>>>(pred, tgt);
}

// Round 10
// 109.009 us; speedup vs baseline: 1.9109x; 1.3728x over previous
//
#include <hip/hip_runtime.h>
#include <math.h>

#define BS 32
#define NQ 900
#define NC 1203
#define NT 100
#define SLOTS 15   // ceil(900/64)
#define K8 8

// Static device-side scratch: no hipMalloc, graph-capture safe, fully
// rewritten every call before any read (deterministic).
__device__ float g_CT[(size_t)BS * NT * NQ];              // 11.5 MB: CT[b][t][q]
__device__ unsigned long long g_topk[(size_t)BS * NT * K8];

// packed sortable key: (monotone f32 bits) << 32 | col ; umin == (value, col) lexicographic
__device__ __forceinline__ unsigned long long packf(float f, int col) {
    unsigned k = __float_as_uint(f);
    k = (k & 0x80000000u) ? ~k : (k | 0x80000000u);
    return ((unsigned long long)k << 32) | (unsigned)col;
}
__device__ __forceinline__ float unpack_val(unsigned long long p) {
    unsigned k = (unsigned)(p >> 32);
    unsigned bits = (k & 0x80000000u) ? (k ^ 0x80000000u) : ~k;
    return __uint_as_float(bits);
}
__device__ __forceinline__ int unpack_col(unsigned long long p) {
    return (int)(p & 0xFFFFFFFFu);
}

// ---------------------------------------------------------------------------
// Kernel 1: cost matrix (math identical to all passing rounds).
// ---------------------------------------------------------------------------
__global__ __launch_bounds__(128) void cost_kernel(
    const float* __restrict__ logits, const float* __restrict__ boxes,
    const int* __restrict__ tlabels, const float* __restrict__ tboxes,
    float* __restrict__ C)
{
    int bq = blockIdx.x;
    int b = bq / NQ, q = bq % NQ;
    int t = threadIdx.x;

    const float* pb = boxes + (size_t)(b * NQ + q) * 4;
    float pcx = pb[0], pcy = pb[1], pw = pb[2], ph = pb[3];

    if (t < NT) {
        int id = tlabels[b * NT + t];
        float x = logits[(size_t)(b * NQ + q) * NC + id];
        float prob = 1.0f / (1.0f + expf(-x));
        float neg = 0.75f * (prob * prob) * (-logf(1.0f - prob + 1e-8f));
        float pos = 0.25f * ((1.0f - prob) * (1.0f - prob)) * (-logf(prob + 1e-8f));
        float cclass = pos - neg;

        const float* tb = tboxes + (size_t)(b * NT + t) * 4;
        float tcx = tb[0], tcy = tb[1], tw = tb[2], th = tb[3];
        float cbbox = fabsf(pcx - tcx) + fabsf(pcy - tcy) + fabsf(pw - tw) + fabsf(ph - th);

        float p0 = pcx - 0.5f * pw, p1 = pcy - 0.5f * ph;
        float p2 = pcx + 0.5f * pw, p3 = pcy + 0.5f * ph;
        float t0 = tcx - 0.5f * tw, t1 = tcy - 0.5f * th;
        float t2 = tcx + 0.5f * tw, t3 = tcy + 0.5f * th;
        float area1 = (p2 - p0) * (p3 - p1);
        float area2 = (t2 - t0) * (t3 - t1);
        float ltx = fmaxf(p0, t0), lty = fmaxf(p1, t1);
        float rbx = fminf(p2, t2), rby = fminf(p3, t3);
        float wx = fmaxf(rbx - ltx, 0.0f), wy = fmaxf(rby - lty, 0.0f);
        float inter = wx * wy;
        float uni = area1 + area2 - inter;
        float iou = inter / uni;
        float l2x = fminf(p0, t0), l2y = fminf(p1, t1);
        float r2x = fmaxf(p2, t2), r2y = fmaxf(p3, t3);
        float hx = fmaxf(r2x - l2x, 0.0f), hy = fmaxf(r2y - l2y, 0.0f);
        float hull = hx * hy;
        float giou = iou - (hull - uni) / hull;

        C[(size_t)(b * NQ + q) * NT + t] =
            5.0f * cbbox + 2.0f * cclass + 2.0f * (-giou);
    }
}

// ---------------------------------------------------------------------------
// Kernel 2: LDS-tiled transpose C[b][q][t] -> g_CT[b][t][q].
// ---------------------------------------------------------------------------
__global__ __launch_bounds__(256) void transpose_kernel(const float* __restrict__ C)
{
    __shared__ float tile[64][101];
    int b = blockIdx.x / 15;
    int chunk = blockIdx.x % 15;
    int q0 = chunk * 64;
    int nq = (q0 + 64 <= NQ) ? 64 : (NQ - q0);
    int tid = threadIdx.x;

    const float* Cb = C + (size_t)b * NQ * NT;
    for (int e = tid; e < nq * NT; e += 256) {
        int qq = e / NT, t = e % NT;
        tile[qq][t] = Cb[(size_t)(q0 + qq) * NT + t];
    }
    __syncthreads();
    float* CTb = g_CT + (size_t)b * NT * NQ;
    for (int e = tid; e < NT * nq; e += 256) {
        int t = e / nq, qq = e % nq;
        CTb[(size_t)t * NQ + q0 + qq] = tile[qq][t];
    }
}

// ---------------------------------------------------------------------------
// Kernel 3: per-row sorted top-8 (value,col) of cost.T, one wave per row.
// Lane-local sorted insertion over 15 elems, then bitonic butterfly merge.
// ---------------------------------------------------------------------------
__global__ __launch_bounds__(64) void topk_kernel()
{
    int bi = blockIdx.x;                    // b*NT + t
    const float* row = g_CT + (size_t)bi * NQ;
    int lane = threadIdx.x;

    unsigned long long r[K8];
    #pragma unroll
    for (int m = 0; m < K8; ++m) r[m] = 0xFFFFFFFFFFFFFFFFull;

    #pragma unroll
    for (int k = 0; k < SLOTS; ++k) {
        int j = (k << 6) + lane;
        if ((k < SLOTS - 1) || (j < NQ)) {
            unsigned long long key = packf(row[j], j);
            #pragma unroll
            for (int m = 0; m < K8; ++m) {     // sorted insert, drop largest
                unsigned long long lo = key < r[m] ? key : r[m];
                unsigned long long hi = key < r[m] ? r[m] : key;
                r[m] = lo; key = hi;
            }
        }
    }
    // butterfly merge of sorted-8 lists
    #pragma unroll
    for (int off = 32; off; off >>= 1) {
        unsigned long long bv[K8], t[K8];
        #pragma unroll
        for (int m = 0; m < K8; ++m) bv[m] = __shfl_down(r[m], off);
        #pragma unroll
        for (int m = 0; m < K8; ++m) {         // lower half of bitonic merge
            unsigned long long x = bv[K8 - 1 - m];
            t[m] = r[m] < x ? r[m] : x;
        }
        #pragma unroll
        for (int d = 4; d; d >>= 1) {          // bitonic sort network
            #pragma unroll
            for (int m = 0; m < K8; ++m) {
                if (!(m & d)) {
                    unsigned long long a = t[m], b2 = t[m | d];
                    t[m] = a < b2 ? a : b2;
                    t[m | d] = a < b2 ? b2 : a;
                }
            }
        }
        #pragma unroll
        for (int m = 0; m < K8; ++m) r[m] = t[m];
    }
    if (lane == 0) {
        #pragma unroll
        for (int m = 0; m < K8; ++m) g_topk[(size_t)bi * K8 + m] = r[m];
    }
}

// ---------------------------------------------------------------------------
// Kernel 4: JV solver, one wave per batch, compact-candidate scans.
// Invariants exploited: never-assigned cols have v==0; #assigned cols <= 100.
// B: greedy  C: ARR (2-visit cap)  D: Dijkstra over assigned set + top-8 free.
// Exact LSA optimum == reference (optimum unique for continuous random costs).
// ---------------------------------------------------------------------------
__global__ __launch_bounds__(64) void jv_kernel(
    float* __restrict__ pred_out, float* __restrict__ tgt_out)
{
    int b = blockIdx.x;
    const float* CTb = g_CT + (size_t)b * NT * NQ;
    int lane = threadIdx.x;
    const double INF = __builtin_huge_val();

    __shared__ double u[NT];
    __shared__ double vsh[NQ];
    __shared__ double distA[128];
    __shared__ int pathA[128];
    __shared__ int asgCols[128];
    __shared__ int pos4col[NQ];
    __shared__ int row4col[NQ];
    __shared__ int col4row[NT];
    __shared__ int aminsh[NT];
    __shared__ int freeRows[NT + 4];
    __shared__ int parked[NT];
    __shared__ int srList[140];
    __shared__ unsigned long long tksh[NT][K8];
    __shared__ unsigned char visits[NT];
    __shared__ int nFreeSh, nParkSh, asgCountSh;

    // ---- phase A: init ----
    for (int j = lane; j < NQ; j += 64) { vsh[j] = 0.0; row4col[j] = 0x7fffffff; pos4col[j] = -1; }
    {
        const unsigned long long* src = g_topk + (size_t)b * NT * K8;
        for (int e = lane; e < NT * K8; e += 64) ((unsigned long long*)tksh)[e] = src[e];
    }
    for (int i = lane; i < NT; i += 64) { col4row[i] = -1; visits[i] = 0; }
    if (lane == 0) { nFreeSh = 0; nParkSh = 0; asgCountSh = 0; }
    __syncthreads();
    for (int i = lane; i < NT; i += 64) {
        unsigned long long tk = tksh[i][0];
        aminsh[i] = unpack_col(tk);
        u[i] = (double)unpack_val(tk);
    }
    __syncthreads();

    // ---- phase B: greedy claim (smallest row wins a contested column) ----
    for (int i = lane; i < NT; i += 64) atomicMin(&row4col[aminsh[i]], i);
    __syncthreads();
    if (lane == 0) {
        int n = 0, cnt = 0;
        for (int i = 0; i < NT; ++i) {
            int j = aminsh[i];
            if (row4col[j] == i) { col4row[i] = j; pos4col[j] = cnt; asgCols[cnt++] = j; }
            else freeRows[n++] = i;
        }
        nFreeSh = n; asgCountSh = cnt;
    }
    __syncthreads();
    for (int j = lane; j < NQ; j += 64)
        if (row4col[j] == 0x7fffffff) row4col[j] = -1;
    __syncthreads();

    // ---- phase C: ARR with 2-visit cap, compact candidates ----
    int guard = 0;
    while (guard++ < 300) {
        int nf = nFreeSh;                          // uniform
        if (nf == 0) break;
        int i = freeRows[nf - 1];                  // uniform
        if (visits[i] >= 2) {
            if (lane == 0) { nFreeSh = nf - 1; parked[nParkSh] = i; nParkSh++; }
            __syncthreads();
            continue;
        }
        if (lane == 0) visits[i]++;
        int asgCount = asgCountSh;
        const float* rowp = CTb + (size_t)i * NQ;

        double m1 = INF, m2 = INF; int j1 = -1;
        bool haveFree = (lane < K8) && (row4col[unpack_col(tksh[i][lane])] < 0);
        unsigned long long bal = __ballot(haveFree);
        if (__popcll(bal) >= 2) {
            #pragma unroll
            for (int s = 0; s < 2; ++s) {
                int pos = lane + (s << 6);
                if (pos < asgCount) {
                    int j = asgCols[pos];
                    double cur = (double)rowp[j] - vsh[j];
                    if (cur < m1) { m2 = m1; m1 = cur; j1 = j; }
                    else if (cur < m2) m2 = cur;
                }
            }
            if (haveFree) {
                unsigned long long tk = tksh[i][lane];
                double cur = (double)unpack_val(tk);   // v == 0 for free cols
                int j = unpack_col(tk);
                if (cur < m1) { m2 = m1; m1 = cur; j1 = j; }
                else if (cur < m2) m2 = cur;
            }
        } else {
            // fallback: full-width scan
            #pragma unroll
            for (int k = 0; k < SLOTS; ++k) {
                int j = (k << 6) + lane;
                if ((k < SLOTS - 1) || (j < NQ)) {
                    double cur = (double)rowp[j] - vsh[j];
                    if (cur < m1) { m2 = m1; m1 = cur; j1 = j; }
                    else if (cur < m2) m2 = cur;
                }
            }
        }
        for (int off = 32; off; off >>= 1) {
            double o1 = __shfl_down(m1, off); int oj = __shfl_down(j1, off);
            double o2 = __shfl_down(m2, off);
            if (o1 < m1 || (o1 == m1 && (unsigned)oj < (unsigned)j1)) { m2 = fmin(m1, o2); m1 = o1; j1 = oj; }
            else m2 = fmin(m2, o1);
        }
        if (lane == 0) {
            u[i] = m2;
            vsh[j1] -= (m2 - m1);
            int inc = row4col[j1];
            row4col[j1] = i; col4row[i] = j1;
            int n = nf - 1;
            if (inc >= 0) { col4row[inc] = -1; freeRows[n++] = inc; }
            else { pos4col[j1] = asgCountSh; asgCols[asgCountSh] = j1; asgCountSh++; }
            nFreeSh = n;
        }
        __syncthreads();
    }
    if (lane == 0) {
        while (nFreeSh > 0) { nFreeSh--; parked[nParkSh] = freeRows[nFreeSh]; nParkSh++; }
    }
    __syncthreads();

    // ---- phase D: Dijkstra over assigned set + top-8 free candidates ----
    int np = nParkSh;
    for (int f = 0; f < np; ++f) {
        int curRow = parked[f];
        int asgCount = asgCountSh;
        double mvA = INF, mvB = INF;
        bool pA = false, pB = false;
        for (int pos = lane; pos < asgCount; pos += 64) distA[pos] = INF;
        double bestFree = INF; int bfCol = -1, bfRow = -1;
        double minVal = 0.0; int i = curRow; int nSr = 1;
        if (lane == 0) srList[0] = curRow;
        __syncthreads();

        int g2 = 0; bool sink = false;
        while (!sink && g2++ < 120) {
            const float* rowp = CTb + (size_t)i * NQ;
            double ui = u[i];
            // assigned-column relax
            {
                int pos = lane;
                if (pos < asgCount && !pA) {
                    int j = asgCols[pos];
                    double cur = minVal + (double)rowp[j] - ui - vsh[j];
                    if (cur < mvA) { mvA = cur; distA[pos] = cur; pathA[pos] = i; }
                }
                pos = lane + 64;
                if (pos < asgCount && !pB) {
                    int j = asgCols[pos];
                    double cur = minVal + (double)rowp[j] - ui - vsh[j];
                    if (cur < mvB) { mvB = cur; distA[pos] = cur; pathA[pos] = i; }
                }
            }
            // free candidate (v == 0): first still-free of row's top-8
            double fc = INF; int fj = -1;
            if (lane < K8) {
                unsigned long long tk = tksh[i][lane];
                int j = unpack_col(tk);
                if (row4col[j] < 0) { fc = minVal + (double)unpack_val(tk) - ui; fj = j; }
            }
            if (__ballot(fc < INF) == 0ull) {
                // fallback: full free-column scan
                #pragma unroll
                for (int k = 0; k < SLOTS; ++k) {
                    int j = (k << 6) + lane;
                    if (((k < SLOTS - 1) || (j < NQ)) && row4col[j] < 0) {
                        double cur = minVal + (double)rowp[j] - ui;
                        if (cur < fc) { fc = cur; fj = j; }
                    }
                }
            }
            // fused butterfly: pop candidate (pv,ppos) and free candidate (fc,fj)
            double pv; int ppos;
            double pva = pA ? INF : mvA, pvb = pB ? INF : mvB;
            if (pvb < pva) { pv = pvb; ppos = lane + 64; } else { pv = pva; ppos = lane; }
            for (int off = 32; off; off >>= 1) {
                double o = __shfl_down(pv, off); int op = __shfl_down(ppos, off);
                if (o < pv || (o == pv && op < ppos)) { pv = o; ppos = op; }
                double of = __shfl_down(fc, off); int ofj = __shfl_down(fj, off);
                if (of < fc || (of == fc && (unsigned)ofj < (unsigned)fj)) { fc = of; fj = ofj; }
            }
            pv = __shfl(pv, 0); ppos = __shfl(ppos, 0);
            fc = __shfl(fc, 0); fj = __shfl(fj, 0);
            if (fc < bestFree) { bestFree = fc; bfCol = fj; bfRow = i; }
            if (bestFree <= pv) { minVal = bestFree; sink = true; }
            else {
                minVal = pv;
                if (lane == (ppos & 63)) { if (ppos < 64) pA = true; else pB = true; }
                i = row4col[asgCols[ppos]];
                if (lane == 0) srList[nSr] = i;
                nSr++;
            }
        }
        __syncthreads();   // distA/pathA/srList stable

        if (lane == 0) {
            u[curRow] += minVal;
            for (int t2 = 1; t2 < nSr; ++t2) {
                int ri = srList[t2];
                u[ri] += minVal - distA[pos4col[col4row[ri]]];   // pre-augment col4row
            }
        }
        {
            int pos = lane;
            if (pos < asgCount && pA) vsh[asgCols[pos]] -= minVal - distA[pos];
            pos = lane + 64;
            if (pos < asgCount && pB) vsh[asgCols[pos]] -= minVal - distA[pos];
        }
        if (lane == 0) {   // augment along pathA, then claim sink
            int j = bfCol, ri = bfRow; int g3 = 0;
            while (g3++ < 128) {
                row4col[j] = ri;
                int tj = col4row[ri]; col4row[ri] = j;
                if (ri == curRow) break;
                j = tj; ri = pathA[pos4col[j]];
            }
            pos4col[bfCol] = asgCountSh; asgCols[asgCountSh] = bfCol; asgCountSh++;
        }
        __syncthreads();
    }

    // ---- epilogue: rank-sort col4row, write indices ----
    for (int i2 = lane; i2 < NT; i2 += 64) {
        int ci = col4row[i2];
        int rank = 0;
        for (int k2 = 0; k2 < NT; ++k2) rank += (col4row[k2] < ci);
        pred_out[b * NT + rank] = (float)ci;
        tgt_out[b * NT + rank] = (float)i2;
    }
}

extern "C" void kernel_launch(void* const* d_in, const int* in_sizes, int n_in,
                              void* d_out, int out_size, void* d_ws, size_t ws_size,
                              hipStream_t stream) {
    const float* logits = (const float*)d_in[0];
    const float* boxes  = (const float*)d_in[1];
    const int*   tlab   = (const int*)d_in[2];
    const float* tboxes = (const float*)d_in[3];

    float* out  = (float*)d_out;
    float* C    = out;                                  // 32*900*100
    float* pred = out + (size_t)BS * NQ * NT;           // 32*100
    float* tgt  = pred + BS * NT;                       // 32*100

    cost_kernel<<<BS * NQ, 128, 0, stream>>>(logits, boxes, tlab, tboxes, C);
    transpose_kernel<<<BS * 15, 256, 0, stream>>>(C);
    topk_kernel<<<BS * NT, 64, 0, stream>>>();
    jv_kernel<<<BS, 64, 0, stream>>>(pred, tgt);
}